// Round 19
// baseline (135.138 us; speedup 1.0000x reference)
//
#include <hip/hip_runtime.h>

#define CH 64
#define HW 4096
#define NN 2048

typedef __attribute__((ext_vector_type(8))) short bf8_t;
typedef __attribute__((ext_vector_type(4))) float f4_t;
#define MFMA16 __builtin_amdgcn_mfma_f32_16x16x32_bf16
#define LOG2E 1.4426950408889634f

static __device__ inline unsigned short f2bf(float f) {
  union { float f; unsigned u; } v; v.f = f;
  unsigned r = v.u + 0x7fff + ((v.u >> 16) & 1);
  return (unsigned short)(r >> 16);
}
static __device__ inline float bf2f(unsigned short u) {
  union { unsigned u; float f; } v; v.u = ((unsigned)u) << 16;
  return v.f;
}

// ---------- conv1 (128->64) + bias -> z, fused BN partial sums ----------
// grid (128, 4): x = position chunk, y = oc quarter (16 oc per block)
__global__ __launch_bounds__(256) void k_conv1(const float* __restrict__ x,
    const float* __restrict__ y, const float* __restrict__ w,
    const float* __restrict__ bias, float* __restrict__ z,
    float2* __restrict__ partials) {
  __shared__ float wl[128][16];  // [cin 0..127][o]
  __shared__ float redS[4][16], redQ[4][16];
  int t = threadIdx.x;
  int yq = blockIdx.y;
  int bx = blockIdx.x;
  for (int i = t; i < 2048; i += 256) {
    int o = i & 15, c = i >> 4;
    wl[c][o] = w[(yq * 16 + o) * 128 + c];
  }
  __syncthreads();
  int b = bx >> 4;
  int s = ((bx & 15) << 8) + t;
  const float* xb = x + b * (CH * HW) + s;
  const float* yb = y + b * (CH * HW) + s;
  float acc[16];
#pragma unroll
  for (int o = 0; o < 16; ++o) acc[o] = 0.f;
  for (int c0 = 0; c0 < 64; c0 += 16) {
    float xr[16], yr[16];
#pragma unroll
    for (int j = 0; j < 16; ++j) {
      xr[j] = xb[(c0 + j) * HW];
      yr[j] = yb[(c0 + j) * HW];
    }
#pragma unroll
    for (int j = 0; j < 16; ++j) {
      int c = c0 + j;
      const float4* wx = reinterpret_cast<const float4*>(&wl[c][0]);
      const float4* wy = reinterpret_cast<const float4*>(&wl[c + 64][0]);
#pragma unroll
      for (int o4 = 0; o4 < 4; ++o4) {
        float4 a = wx[o4], bb = wy[o4];
        acc[4 * o4 + 0] += xr[j] * a.x + yr[j] * bb.x;
        acc[4 * o4 + 1] += xr[j] * a.y + yr[j] * bb.y;
        acc[4 * o4 + 2] += xr[j] * a.z + yr[j] * bb.z;
        acc[4 * o4 + 3] += xr[j] * a.w + yr[j] * bb.w;
      }
    }
  }
  float* zb = z + b * (CH * HW) + s;
  int lane = t & 63, wv = t >> 6;
#pragma unroll
  for (int o = 0; o < 16; ++o) {
    float v = acc[o] + bias[yq * 16 + o];
    zb[(yq * 16 + o) * HW] = v;
    float a1 = v, a2 = v * v;
    for (int off = 32; off; off >>= 1) {
      a1 += __shfl_xor(a1, off);
      a2 += __shfl_xor(a2, off);
    }
    if (lane == 0) { redS[wv][o] = a1; redQ[wv][o] = a2; }
  }
  __syncthreads();
  if (t < 16) {
    float2 pp;
    pp.x = redS[0][t] + redS[1][t] + redS[2][t] + redS[3][t];
    pp.y = redQ[0][t] + redQ[1][t] + redQ[2][t] + redQ[3][t];
    partials[((bx << 2) + yq) * 16 + t] = pp;
  }
}

// ---------- prep: reduce BN stats, fold weights (theta scaled by log2e) ----------
__global__ __launch_bounds__(256) void k_prep1(const float2* __restrict__ partials,
    const float* __restrict__ phw, const float* __restrict__ thw,
    const float* __restrict__ gw, const float* __restrict__ mask_w,
    const float* __restrict__ g1, const float* __restrict__ b1,
    float* __restrict__ effw, float* __restrict__ effb,
    unsigned short* __restrict__ wMbf, float* __restrict__ scA,
    float* __restrict__ shA) {
  __shared__ float scS[64], shS[64];
  int t = threadIdx.x;
  if (t < 64) {
    int yq = t >> 4, o = t & 15;
    float S = 0.f, S2 = 0.f;
    for (int cb = 0; cb < 128; ++cb) {
      float2 p = partials[((cb << 2) + yq) * 16 + o];
      S += p.x; S2 += p.y;
    }
    float mean = S * (1.f / 32768.f);
    float var = S2 * (1.f / 32768.f) - mean * mean;
    float is = rsqrtf(var + 1e-5f);
    float sc = g1[t] * is;
    float sh = b1[t] - mean * sc;
    scS[t] = sc; shS[t] = sh;
    scA[t] = sc; shA[t] = sh;
  }
  __syncthreads();
  for (int i = t; i < 6144; i += 256) {
    int p = i >> 11, c = (i >> 5) & 63, ic = i & 31;
    const float* wp = (p == 0) ? phw : (p == 1) ? thw : gw;
    float scale = (p == 1) ? LOG2E : 1.0f;
    effw[i] = wp[ic * 64 + c] * scS[c] * scale;
  }
  for (int i = t; i < 2048; i += 256)
    wMbf[i] = f2bf(mask_w[i]);      // [oc][ic] row-major, bf16
  if (t < 96) {
    int p = t >> 5, ic = t & 31;
    const float* wp = (p == 0) ? phw : (p == 1) ? thw : gw;
    float scale = (p == 1) ? LOG2E : 1.0f;
    float s_ = 0.f;
    for (int c = 0; c < 64; ++c) s_ += wp[ic * 64 + c] * shS[c];
    effb[t] = s_ * scale;
  }
}

// ---------- projections: grid (128, 6), y = p*2 + ic-half ----------
__global__ __launch_bounds__(256) void k_proj(const float* __restrict__ z,
    const float* __restrict__ effw, const float* __restrict__ effb,
    unsigned short* __restrict__ phiT, unsigned short* __restrict__ thetaT,
    unsigned short* __restrict__ gB) {
  int t = threadIdx.x;
  int p = blockIdx.y >> 1;
  int ih = blockIdx.y & 1;
  int bx = blockIdx.x;
  int b = bx >> 4;
  int s = ((bx & 15) << 8) + t;
  int n = s & 2047, hi = s >> 11;
  const float* zb = z + b * (CH * HW) + s;
  const float* wp = effw + p * 2048 + ih * 16;
  float acc[16];
#pragma unroll
  for (int j = 0; j < 16; ++j) acc[j] = effb[p * 32 + ih * 16 + j];
  for (int c0 = 0; c0 < 64; c0 += 16) {
    float zr[16];
#pragma unroll
    for (int j = 0; j < 16; ++j) zr[j] = zb[(c0 + j) * HW];
#pragma unroll
    for (int j = 0; j < 16; ++j) {
      const float4* w4 = reinterpret_cast<const float4*>(wp + (c0 + j) * 32);
#pragma unroll
      for (int q = 0; q < 4; ++q) {
        float4 wv = w4[q];
        acc[4 * q + 0] += zr[j] * wv.x;
        acc[4 * q + 1] += zr[j] * wv.y;
        acc[4 * q + 2] += zr[j] * wv.z;
        acc[4 * q + 3] += zr[j] * wv.w;
      }
    }
  }
  if (p < 2) {
    unsigned short* ob = (p == 0 ? phiT : thetaT) + b * (NN * 64) + n * 64 + hi * 32 + ih * 16;
    unsigned int pk[8];
#pragma unroll
    for (int q = 0; q < 8; ++q)
      pk[q] = (unsigned int)f2bf(acc[2 * q]) | ((unsigned int)f2bf(acc[2 * q + 1]) << 16);
    uint4* o4 = reinterpret_cast<uint4*>(ob);
    o4[0] = make_uint4(pk[0], pk[1], pk[2], pk[3]);
    o4[1] = make_uint4(pk[4], pk[5], pk[6], pk[7]);
  } else {
    unsigned short* ob = gB + b * (64 * NN) + n;
#pragma unroll
    for (int j = 0; j < 16; ++j) ob[(2 * (ih * 16 + j) + hi) * NN] = f2bf(acc[j]);
  }
}

// ---------- pass A: quarter column sums of exp2(S'); LDS-staged theta WITH barriers
//            (R17-exact; barrier-free variant raced or was co-suspect in R18) ----------
__global__ __launch_bounds__(256) void k_colsum(const unsigned short* __restrict__ thetaT,
    const unsigned short* __restrict__ phiT, float* __restrict__ csum) {
  int bx = blockIdx.x;
  int b = blockIdx.y;
  int mtile = bx >> 2, nq = bx & 3;
  int m0 = mtile << 6;
  int t = threadIdx.x; int lane = t & 63; int w = t >> 6;
  const unsigned short* pT = phiT + b * (NN * 64);
  const unsigned short* tT = thetaT + b * (NN * 64);
  int l15 = lane & 15, lg = lane >> 4;
  __shared__ unsigned short thS[64][72];  // 144B stride (9x16B): all b128 aligned
  __shared__ float red[4][4][16];
  int srow = t >> 2, spart = t & 3;
  bf8_t bf[4][2];
#pragma unroll
  for (int mt = 0; mt < 4; ++mt)
#pragma unroll
    for (int kh = 0; kh < 2; ++kh)
      bf[mt][kh] = *(const bf8_t*)(pT + (m0 + 16 * mt + l15) * 64 + kh * 32 + lg * 8);
  float cs[4] = {0.f, 0.f, 0.f, 0.f};
  for (int nt = nq * 8; nt < nq * 8 + 8; ++nt) {
    __syncthreads();
    {
      const uint4* gt = reinterpret_cast<const uint4*>(tT + (nt * 64 + srow) * 64 + spart * 16);
      uint4* lt = reinterpret_cast<uint4*>(&thS[srow][spart * 16]);
      lt[0] = gt[0];
      lt[1] = gt[1];
    }
    __syncthreads();
    bf8_t a0 = *(const bf8_t*)&thS[w * 16 + l15][lg * 8];
    bf8_t a1 = *(const bf8_t*)&thS[w * 16 + l15][32 + lg * 8];
#pragma unroll
    for (int mt = 0; mt < 4; ++mt) {
      f4_t d = {0.f, 0.f, 0.f, 0.f};
      d = MFMA16(a0, bf[mt][0], d, 0, 0, 0);
      d = MFMA16(a1, bf[mt][1], d, 0, 0, 0);
      cs[mt] += __builtin_amdgcn_exp2f(d[0]) + __builtin_amdgcn_exp2f(d[1]) +
                __builtin_amdgcn_exp2f(d[2]) + __builtin_amdgcn_exp2f(d[3]);
    }
  }
#pragma unroll
  for (int mt = 0; mt < 4; ++mt) {
    float v = cs[mt];
    v += __shfl_xor(v, 16);
    v += __shfl_xor(v, 32);
    if (lane < 16) red[w][mt][lane] = v;
  }
  __syncthreads();
  if (t < 64) {
    int mt = t >> 4, col = t & 15;
    float s = red[0][mt][col] + red[1][mt][col] + red[2][mt][col] + red[3][mt][col];
    csum[b * 8192 + nq * 2048 + m0 + mt * 16 + col] = s;
  }
}

// ---------- scale gB in-place by softmax reciprocal (sum 4 quarters) ----------
__global__ __launch_bounds__(256) void k_gscale(const float* __restrict__ csum,
    unsigned short* __restrict__ gB) {
  int bx = blockIdx.x;             // 512: b = bx>>6, c = bx&63
  int b = bx >> 6, c = bx & 63;
  int t = threadIdx.x;
  int m = t * 8;
  const float* cs = csum + b * 8192;
  unsigned short* g = gB + b * (64 * NN) + c * NN + m;
  float r[8];
#pragma unroll
  for (int j = 0; j < 8; ++j) {
    float s = cs[m + j] + cs[2048 + m + j] + cs[4096 + m + j] + cs[6144 + m + j];
    r[j] = 1.f / s;
  }
  uint4 gv = *(const uint4*)g;
  unsigned int* gd = (unsigned int*)&gv;
  uint4 out;
  unsigned int* od = (unsigned int*)&out;
#pragma unroll
  for (int q = 0; q < 4; ++q) {
    float lo = bf2f((unsigned short)(gd[q] & 0xffff)) * r[2 * q];
    float hi = bf2f((unsigned short)(gd[q] >> 16)) * r[2 * q + 1];
    od[q] = (unsigned int)f2bf(lo) | ((unsigned int)f2bf(hi) << 16);
  }
  *(uint4*)g = out;
}

// ---------- pass B: double-buffered phi/g tiles, ONE barrier per mi,
//            swapped-S, in-register P; grid (128, 8) ----------
// x = ntile*4 + mq ; writes obufP[mq][b][pos][ic]  (pos = (c&1)*2048+n, ic = c>>1)
__global__ __launch_bounds__(256) void k_pv(const unsigned short* __restrict__ thetaT,
    const unsigned short* __restrict__ phiT, const unsigned short* __restrict__ gB,
    unsigned short* __restrict__ obufP) {
  int bx = blockIdx.x;
  int b = blockIdx.y;
  int ntile = bx >> 2, mq = bx & 3;
  int n0 = ntile << 6;
  int t = threadIdx.x; int lane = t & 63; int w = t >> 6;
  int l15 = lane & 15, lg = lane >> 4;
  const unsigned short* tT = thetaT + b * (NN * 64);
  const unsigned short* pT = phiT + b * (NN * 64);
  const unsigned short* gb = gB + b * (64 * NN);
  __shared__ unsigned short phiS[2][64][72];  // double-buffered, 144B row stride
  __shared__ unsigned short gS[2][64][72];
  __shared__ unsigned int P_u[4][16][33];     // per-wave P, u32-packed
  int nrow = n0 + 16 * w + l15;
  bf8_t at0 = *(const bf8_t*)(tT + nrow * 64 + lg * 8);
  bf8_t at1 = *(const bf8_t*)(tT + nrow * 64 + 32 + lg * 8);
  int srow = t >> 2, spart = t & 3;
  f4_t oacc[4];
#pragma unroll
  for (int ct = 0; ct < 4; ++ct) oacc[ct] = (f4_t){0.f, 0.f, 0.f, 0.f};
  for (int mi = 0; mi < 8; ++mi) {
    int m0 = (mq * 8 + mi) << 6;
    int pb = mi & 1;
    // stage tile mi into buffer pb; safe with single barrier: any wave here has
    // passed barrier mi-1, whose waitcnt drain implies all waves' mi-2 LDS reads done.
    {
      const uint4* gp = reinterpret_cast<const uint4*>(pT + (m0 + srow) * 64 + spart * 16);
      uint4* lp = reinterpret_cast<uint4*>(&phiS[pb][srow][spart * 16]);
      lp[0] = gp[0];
      lp[1] = gp[1];
      const uint4* gg = reinterpret_cast<const uint4*>(gb + srow * NN + m0 + spart * 16);
      uint4* lg_ = reinterpret_cast<uint4*>(&gS[pb][srow][spart * 16]);
      lg_[0] = gg[0];
      lg_[1] = gg[1];
    }
    __syncthreads();  // tile pb ready for all waves
#pragma unroll
    for (int mt = 0; mt < 4; ++mt) {
      bf8_t b0 = *(const bf8_t*)&phiS[pb][16 * mt + l15][lg * 8];
      bf8_t b1 = *(const bf8_t*)&phiS[pb][16 * mt + l15][32 + lg * 8];
      f4_t d = {0.f, 0.f, 0.f, 0.f};
      d = MFMA16(b0, at0, d, 0, 0, 0);
      d = MFMA16(b1, at1, d, 0, 0, 0);
      float e0 = __builtin_amdgcn_exp2f(d[0]);
      float e1 = __builtin_amdgcn_exp2f(d[1]);
      float e2 = __builtin_amdgcn_exp2f(d[2]);
      float e3 = __builtin_amdgcn_exp2f(d[3]);
      unsigned int p01, p23;
      asm("v_cvt_pk_bf16_f32 %0, %1, %2" : "=v"(p01) : "v"(e0), "v"(e1));
      asm("v_cvt_pk_bf16_f32 %0, %1, %2" : "=v"(p23) : "v"(e2), "v"(e3));
      P_u[w][l15][8 * mt + 2 * lg] = p01;
      P_u[w][l15][8 * mt + 2 * lg + 1] = p23;
    }
    bf8_t ap0 = *(const bf8_t*)&P_u[w][l15][4 * lg];
    bf8_t ap1 = *(const bf8_t*)&P_u[w][l15][16 + 4 * lg];
#pragma unroll
    for (int ct = 0; ct < 4; ++ct) {
      bf8_t g0 = *(const bf8_t*)&gS[pb][16 * ct + l15][lg * 8];
      bf8_t g1 = *(const bf8_t*)&gS[pb][16 * ct + l15][32 + lg * 8];
      oacc[ct] = MFMA16(ap0, g0, oacc[ct], 0, 0, 0);
      oacc[ct] = MFMA16(ap1, g1, oacc[ct], 0, 0, 0);
    }
  }
  unsigned short* ob = obufP + (mq * 8 + b) * 131072;
#pragma unroll
  for (int ct = 0; ct < 4; ++ct) {
    int c = 16 * ct + l15;
    int nb = n0 + 16 * w + lg * 4;
    int ic = c >> 1;
    int posb = (c & 1) * 2048 + nb;
#pragma unroll
    for (int q = 0; q < 4; ++q)
      ob[(posb + q) * 32 + ic] = f2bf(oacc[ct][q]);
  }
}

// ---------- mask conv via MFMA (mq folded into acc) + residual + pool; grid 512 ----------
__global__ __launch_bounds__(256) void k_mask(const unsigned short* __restrict__ obufP,
    const unsigned short* __restrict__ wMbf, const float* __restrict__ scA,
    const float* __restrict__ shA, float* __restrict__ zio,
    float* __restrict__ poolpart) {
  __shared__ unsigned short wMl[64][40];  // [oc][ic] bf16, 80B stride
  __shared__ float red[4][4][16];
  int t = threadIdx.x, lane = t & 63, w = t >> 6;
  int l15 = lane & 15, lg = lane >> 4;
  int bx = blockIdx.x;
  int b = bx >> 6;
  int p0 = (bx & 63) * 64 + w * 16;
  {
    int row = t >> 2, part = t & 3;  // byte addr = row*80 + part*16 : aligned
    *(uint4*)&wMl[row][part * 8] = *(const uint4*)(wMbf + row * 32 + part * 8);
  }
  __syncthreads();
  bf8_t bw[4];
#pragma unroll
  for (int ct = 0; ct < 4; ++ct)
    bw[ct] = *(const bf8_t*)&wMl[16 * ct + l15][lg * 8];
  f4_t acc[4];
#pragma unroll
  for (int ct = 0; ct < 4; ++ct) acc[ct] = (f4_t){0.f, 0.f, 0.f, 0.f};
#pragma unroll
  for (int mq = 0; mq < 4; ++mq) {
    bf8_t a = *(const bf8_t*)(obufP + ((mq * 8 + b) << 17) + (p0 + l15) * 32 + lg * 8);
#pragma unroll
    for (int ct = 0; ct < 4; ++ct)
      acc[ct] = MFMA16(a, bw[ct], acc[ct], 0, 0, 0);
  }
  float* zb = zio + b * (CH * HW);
#pragma unroll
  for (int ct = 0; ct < 4; ++ct) {
    int oc = 16 * ct + l15;
    int pg = p0 + 4 * lg;
    float4 zv = *(const float4*)(zb + oc * HW + pg);
    float sc = scA[oc], sh = shA[oc];
    float4 r;
    r.x = acc[ct][0] + sc * zv.x + sh;
    r.y = acc[ct][1] + sc * zv.y + sh;
    r.z = acc[ct][2] + sc * zv.z + sh;
    r.w = acc[ct][3] + sc * zv.w + sh;
    *(float4*)(zb + oc * HW + pg) = r;
    float s = r.x + r.y + r.z + r.w;
    s += __shfl_xor(s, 16);
    s += __shfl_xor(s, 32);
    if (lg == 0) red[w][ct][l15] = s;
  }
  __syncthreads();
  if (t < 64) {
    int ct = t >> 4, cl = t & 15;
    poolpart[bx * 64 + ct * 16 + cl] =
        red[0][ct][cl] + red[1][ct][cl] + red[2][ct][cl] + red[3][ct][cl];
  }
}

// ---------- head ----------
__global__ __launch_bounds__(256) void k_head(const float* __restrict__ poolpart,
    const float* __restrict__ fcw, const float* __restrict__ fcb,
    const float* __restrict__ bg, const float* __restrict__ bb,
    const float* __restrict__ lx, const float* __restrict__ ly,
    float* __restrict__ outLogit) {
  __shared__ float poolS[8][64];
  __shared__ float fv[8][2];
  __shared__ float gate[8][2];
  int t = threadIdx.x;
  for (int idx = t; idx < 512; idx += 256) {
    int b = idx >> 6, oc = idx & 63;
    float s = 0.f;
    for (int ch = 0; ch < 64; ++ch)
      s += poolpart[((b << 6) + ch) * 64 + oc];
    poolS[b][oc] = s * (1.f / 4096.f);
  }
  __syncthreads();
  if (t < 16) {
    int b = t >> 1, k = t & 1;
    float s = fcb[k];
    for (int c = 0; c < 64; ++c) s += poolS[b][c] * fcw[k * 64 + c];
    fv[b][k] = s;
  }
  __syncthreads();
  if (t < 2) {
    float m = 0.f;
    for (int b = 0; b < 8; ++b) m += fv[b][t];
    m *= 0.125f;
    float v = 0.f;
    for (int b = 0; b < 8; ++b) { float d = fv[b][t] - m; v += d * d; }
    v *= 0.125f;
    float is = rsqrtf(v + 1e-5f);
    for (int b = 0; b < 8; ++b) gate[b][t] = bg[t] * (fv[b][t] - m) * is + bb[t];
  }
  __syncthreads();
  if (t < 8) {
    float a = fmaxf(gate[t][0], 0.f), b2 = fmaxf(gate[t][1], 0.f);
    float mx = fmaxf(a, b2);
    float e0 = __expf(a - mx), e1 = __expf(b2 - mx);
    float inv = 1.f / (e0 + e1);
    gate[t][0] = e0 * inv;
    gate[t][1] = e1 * inv;
  }
  __syncthreads();
  for (int i = t; i < 800; i += 256) {
    int b = i / 100;
    outLogit[i] = gate[b][0] * lx[i] + gate[b][1] * ly[i];
  }
}

extern "C" void kernel_launch(void* const* d_in, const int* in_sizes, int n_in,
                              void* d_out, int out_size, void* d_ws, size_t ws_size,
                              hipStream_t stream) {
  (void)in_sizes; (void)n_in; (void)out_size; (void)ws_size;
  const float* x = (const float*)d_in[0];
  const float* y = (const float*)d_in[1];
  const float* logitx = (const float*)d_in[2];
  const float* logity = (const float*)d_in[3];
  const float* conv1_w = (const float*)d_in[4];
  const float* conv1_b = (const float*)d_in[5];
  const float* bn1_g = (const float*)d_in[6];
  const float* bn1_b = (const float*)d_in[7];
  const float* phi_w = (const float*)d_in[8];
  const float* theta_w = (const float*)d_in[9];
  const float* g_w = (const float*)d_in[10];
  const float* mask_w = (const float*)d_in[11];
  const float* fc_w = (const float*)d_in[12];
  const float* fc_b = (const float*)d_in[13];
  const float* bnv_g = (const float*)d_in[14];
  const float* bnv_b = (const float*)d_in[15];

  unsigned short* U = (unsigned short*)d_ws;
  float* F = (float*)d_ws;
  unsigned short* thetaT = U;                   // 2 MB
  unsigned short* phiT   = U + 1048576;         // 2 MB
  unsigned short* gB     = U + 2097152;         // 2 MB
  unsigned short* obufP  = U + 3145728;         // 8 MB (4 mq x 8 b x 4096 pos x 32 ic)
  float* csum      = F + 3670016;               // 65536 floats (b*8192 stride)
  float* poolpart  = F + 3670016;               // ALIAS of csum: csum consumed by gscale
                                                // (kernel 5) before k_mask (kernel 7) writes
  float2* partials = (float2*)(F + 3735552);    // 128*4*16 float2 (16384 floats)
  float* effw      = F + 3751936;               // 6144
  float* effb      = F + 3758080;               // 96 (pad 128)
  unsigned short* wMbf = (unsigned short*)(F + 3758208);  // 2048 shorts (1024 floats)
  float* scA       = F + 3759232;               // 64
  float* shA       = F + 3759296;               // 64 -> end F+3759360 (~14.3 MB)

  float* zout = (float*)d_out;        // z then feasc in-place
  float* lout = zout + 2097152;       // logit

  k_conv1<<<dim3(128, 4), 256, 0, stream>>>(x, y, conv1_w, conv1_b, zout, partials);
  k_prep1<<<1, 256, 0, stream>>>(partials, phi_w, theta_w, g_w, mask_w,
                                 bn1_g, bn1_b, effw, effb, wMbf, scA, shA);
  k_proj<<<dim3(128, 6), 256, 0, stream>>>(zout, effw, effb, phiT, thetaT, gB);
  k_colsum<<<dim3(128, 8), 256, 0, stream>>>(thetaT, phiT, csum);
  k_gscale<<<512, 256, 0, stream>>>(csum, gB);
  k_pv<<<dim3(128, 8), 256, 0, stream>>>(thetaT, phiT, gB, obufP);
  k_mask<<<512, 256, 0, stream>>>(obufP, wMbf, scA, shA, zout, poolpart);
  k_head<<<1, 256, 0, stream>>>(poolpart, fc_w, fc_b, bnv_g, bnv_b, logitx, logity, lout);
}

// Round 20
// 134.256 us; speedup vs baseline: 1.0066x; 1.0066x over previous
//
#include <hip/hip_runtime.h>

#define CH 64
#define HW 4096
#define NN 2048

typedef __attribute__((ext_vector_type(8))) short bf8_t;
typedef __attribute__((ext_vector_type(4))) float f4_t;
#define MFMA16 __builtin_amdgcn_mfma_f32_16x16x32_bf16
#define LOG2E 1.4426950408889634f

static __device__ inline unsigned short f2bf(float f) {
  union { float f; unsigned u; } v; v.f = f;
  unsigned r = v.u + 0x7fff + ((v.u >> 16) & 1);
  return (unsigned short)(r >> 16);
}
static __device__ inline float bf2f(unsigned short u) {
  union { unsigned u; float f; } v; v.u = ((unsigned)u) << 16;
  return v.f;
}

// ---------- conv1 (128->64) + bias -> z, fused BN partial sums ----------
// grid (128, 4): x = position chunk, y = oc quarter (16 oc per block)
__global__ __launch_bounds__(256) void k_conv1(const float* __restrict__ x,
    const float* __restrict__ y, const float* __restrict__ w,
    const float* __restrict__ bias, float* __restrict__ z,
    float2* __restrict__ partials) {
  __shared__ float wl[128][16];  // [cin 0..127][o]
  __shared__ float redS[4][16], redQ[4][16];
  int t = threadIdx.x;
  int yq = blockIdx.y;
  int bx = blockIdx.x;
  for (int i = t; i < 2048; i += 256) {
    int o = i & 15, c = i >> 4;
    wl[c][o] = w[(yq * 16 + o) * 128 + c];
  }
  __syncthreads();
  int b = bx >> 4;
  int s = ((bx & 15) << 8) + t;
  const float* xb = x + b * (CH * HW) + s;
  const float* yb = y + b * (CH * HW) + s;
  float acc[16];
#pragma unroll
  for (int o = 0; o < 16; ++o) acc[o] = 0.f;
  for (int c0 = 0; c0 < 64; c0 += 16) {
    float xr[16], yr[16];
#pragma unroll
    for (int j = 0; j < 16; ++j) {
      xr[j] = xb[(c0 + j) * HW];
      yr[j] = yb[(c0 + j) * HW];
    }
#pragma unroll
    for (int j = 0; j < 16; ++j) {
      int c = c0 + j;
      const float4* wx = reinterpret_cast<const float4*>(&wl[c][0]);
      const float4* wy = reinterpret_cast<const float4*>(&wl[c + 64][0]);
#pragma unroll
      for (int o4 = 0; o4 < 4; ++o4) {
        float4 a = wx[o4], bb = wy[o4];
        acc[4 * o4 + 0] += xr[j] * a.x + yr[j] * bb.x;
        acc[4 * o4 + 1] += xr[j] * a.y + yr[j] * bb.y;
        acc[4 * o4 + 2] += xr[j] * a.z + yr[j] * bb.z;
        acc[4 * o4 + 3] += xr[j] * a.w + yr[j] * bb.w;
      }
    }
  }
  float* zb = z + b * (CH * HW) + s;
  int lane = t & 63, wv = t >> 6;
#pragma unroll
  for (int o = 0; o < 16; ++o) {
    float v = acc[o] + bias[yq * 16 + o];
    zb[(yq * 16 + o) * HW] = v;
    float a1 = v, a2 = v * v;
    for (int off = 32; off; off >>= 1) {
      a1 += __shfl_xor(a1, off);
      a2 += __shfl_xor(a2, off);
    }
    if (lane == 0) { redS[wv][o] = a1; redQ[wv][o] = a2; }
  }
  __syncthreads();
  if (t < 16) {
    float2 pp;
    pp.x = redS[0][t] + redS[1][t] + redS[2][t] + redS[3][t];
    pp.y = redQ[0][t] + redQ[1][t] + redQ[2][t] + redQ[3][t];
    partials[((bx << 2) + yq) * 16 + t] = pp;
  }
}

// ---------- prep: reduce BN stats, fold weights (theta scaled by log2e) ----------
__global__ __launch_bounds__(256) void k_prep1(const float2* __restrict__ partials,
    const float* __restrict__ phw, const float* __restrict__ thw,
    const float* __restrict__ gw, const float* __restrict__ mask_w,
    const float* __restrict__ g1, const float* __restrict__ b1,
    float* __restrict__ effw, float* __restrict__ effb,
    unsigned short* __restrict__ wMbf, float* __restrict__ scA,
    float* __restrict__ shA) {
  __shared__ float scS[64], shS[64];
  int t = threadIdx.x;
  if (t < 64) {
    int yq = t >> 4, o = t & 15;
    float S = 0.f, S2 = 0.f;
    for (int cb = 0; cb < 128; ++cb) {
      float2 p = partials[((cb << 2) + yq) * 16 + o];
      S += p.x; S2 += p.y;
    }
    float mean = S * (1.f / 32768.f);
    float var = S2 * (1.f / 32768.f) - mean * mean;
    float is = rsqrtf(var + 1e-5f);
    float sc = g1[t] * is;
    float sh = b1[t] - mean * sc;
    scS[t] = sc; shS[t] = sh;
    scA[t] = sc; shA[t] = sh;
  }
  __syncthreads();
  for (int i = t; i < 6144; i += 256) {
    int p = i >> 11, c = (i >> 5) & 63, ic = i & 31;
    const float* wp = (p == 0) ? phw : (p == 1) ? thw : gw;
    float scale = (p == 1) ? LOG2E : 1.0f;
    effw[i] = wp[ic * 64 + c] * scS[c] * scale;
  }
  for (int i = t; i < 2048; i += 256)
    wMbf[i] = f2bf(mask_w[i]);      // [oc][ic] row-major, bf16
  if (t < 96) {
    int p = t >> 5, ic = t & 31;
    const float* wp = (p == 0) ? phw : (p == 1) ? thw : gw;
    float scale = (p == 1) ? LOG2E : 1.0f;
    float s_ = 0.f;
    for (int c = 0; c < 64; ++c) s_ += wp[ic * 64 + c] * shS[c];
    effb[t] = s_ * scale;
  }
}

// ---------- projections: grid (128, 6), y = p*2 + ic-half ----------
__global__ __launch_bounds__(256) void k_proj(const float* __restrict__ z,
    const float* __restrict__ effw, const float* __restrict__ effb,
    unsigned short* __restrict__ phiT, unsigned short* __restrict__ thetaT,
    unsigned short* __restrict__ gB) {
  int t = threadIdx.x;
  int p = blockIdx.y >> 1;
  int ih = blockIdx.y & 1;
  int bx = blockIdx.x;
  int b = bx >> 4;
  int s = ((bx & 15) << 8) + t;
  int n = s & 2047, hi = s >> 11;
  const float* zb = z + b * (CH * HW) + s;
  const float* wp = effw + p * 2048 + ih * 16;
  float acc[16];
#pragma unroll
  for (int j = 0; j < 16; ++j) acc[j] = effb[p * 32 + ih * 16 + j];
  for (int c0 = 0; c0 < 64; c0 += 16) {
    float zr[16];
#pragma unroll
    for (int j = 0; j < 16; ++j) zr[j] = zb[(c0 + j) * HW];
#pragma unroll
    for (int j = 0; j < 16; ++j) {
      const float4* w4 = reinterpret_cast<const float4*>(wp + (c0 + j) * 32);
#pragma unroll
      for (int q = 0; q < 4; ++q) {
        float4 wv = w4[q];
        acc[4 * q + 0] += zr[j] * wv.x;
        acc[4 * q + 1] += zr[j] * wv.y;
        acc[4 * q + 2] += zr[j] * wv.z;
        acc[4 * q + 3] += zr[j] * wv.w;
      }
    }
  }
  if (p < 2) {
    unsigned short* ob = (p == 0 ? phiT : thetaT) + b * (NN * 64) + n * 64 + hi * 32 + ih * 16;
    unsigned int pk[8];
#pragma unroll
    for (int q = 0; q < 8; ++q)
      pk[q] = (unsigned int)f2bf(acc[2 * q]) | ((unsigned int)f2bf(acc[2 * q + 1]) << 16);
    uint4* o4 = reinterpret_cast<uint4*>(ob);
    o4[0] = make_uint4(pk[0], pk[1], pk[2], pk[3]);
    o4[1] = make_uint4(pk[4], pk[5], pk[6], pk[7]);
  } else {
    unsigned short* ob = gB + b * (64 * NN) + n;
#pragma unroll
    for (int j = 0; j < 16; ++j) ob[(2 * (ih * 16 + j) + hi) * NN] = f2bf(acc[j]);
  }
}

// ---------- pass A: quarter column sums of exp2(S'); LDS-staged theta; grid (128, 8) ----------
__global__ __launch_bounds__(256) void k_colsum(const unsigned short* __restrict__ thetaT,
    const unsigned short* __restrict__ phiT, float* __restrict__ csum) {
  int bx = blockIdx.x;
  int b = blockIdx.y;
  int mtile = bx >> 2, nq = bx & 3;
  int m0 = mtile << 6;
  int t = threadIdx.x; int lane = t & 63; int w = t >> 6;
  const unsigned short* pT = phiT + b * (NN * 64);
  const unsigned short* tT = thetaT + b * (NN * 64);
  int l15 = lane & 15, lg = lane >> 4;
  __shared__ unsigned short thS[64][72];  // 144B stride (9x16B): all b128 aligned
  __shared__ float red[4][4][16];
  int srow = t >> 2, spart = t & 3;
  bf8_t bf[4][2];
#pragma unroll
  for (int mt = 0; mt < 4; ++mt)
#pragma unroll
    for (int kh = 0; kh < 2; ++kh)
      bf[mt][kh] = *(const bf8_t*)(pT + (m0 + 16 * mt + l15) * 64 + kh * 32 + lg * 8);
  float cs[4] = {0.f, 0.f, 0.f, 0.f};
  for (int nt = nq * 8; nt < nq * 8 + 8; ++nt) {
    __syncthreads();
    {
      const uint4* gt = reinterpret_cast<const uint4*>(tT + (nt * 64 + srow) * 64 + spart * 16);
      uint4* lt = reinterpret_cast<uint4*>(&thS[srow][spart * 16]);
      lt[0] = gt[0];
      lt[1] = gt[1];
    }
    __syncthreads();
    bf8_t a0 = *(const bf8_t*)&thS[w * 16 + l15][lg * 8];
    bf8_t a1 = *(const bf8_t*)&thS[w * 16 + l15][32 + lg * 8];
#pragma unroll
    for (int mt = 0; mt < 4; ++mt) {
      f4_t d = {0.f, 0.f, 0.f, 0.f};
      d = MFMA16(a0, bf[mt][0], d, 0, 0, 0);
      d = MFMA16(a1, bf[mt][1], d, 0, 0, 0);
      cs[mt] += __builtin_amdgcn_exp2f(d[0]) + __builtin_amdgcn_exp2f(d[1]) +
                __builtin_amdgcn_exp2f(d[2]) + __builtin_amdgcn_exp2f(d[3]);
    }
  }
#pragma unroll
  for (int mt = 0; mt < 4; ++mt) {
    float v = cs[mt];
    v += __shfl_xor(v, 16);
    v += __shfl_xor(v, 32);
    if (lane < 16) red[w][mt][lane] = v;
  }
  __syncthreads();
  if (t < 64) {
    int mt = t >> 4, col = t & 15;
    float s = red[0][mt][col] + red[1][mt][col] + red[2][mt][col] + red[3][mt][col];
    csum[b * 8192 + nq * 2048 + m0 + mt * 16 + col] = s;
  }
}

// ---------- scale gB in-place by softmax reciprocal (sum 4 quarters) ----------
__global__ __launch_bounds__(256) void k_gscale(const float* __restrict__ csum,
    unsigned short* __restrict__ gB) {
  int bx = blockIdx.x;             // 512: b = bx>>6, c = bx&63
  int b = bx >> 6, c = bx & 63;
  int t = threadIdx.x;
  int m = t * 8;
  const float* cs = csum + b * 8192;
  unsigned short* g = gB + b * (64 * NN) + c * NN + m;
  float r[8];
#pragma unroll
  for (int j = 0; j < 8; ++j) {
    float s = cs[m + j] + cs[2048 + m + j] + cs[4096 + m + j] + cs[6144 + m + j];
    r[j] = 1.f / s;
  }
  uint4 gv = *(const uint4*)g;
  unsigned int* gd = (unsigned int*)&gv;
  uint4 out;
  unsigned int* od = (unsigned int*)&out;
#pragma unroll
  for (int q = 0; q < 4; ++q) {
    float lo = bf2f((unsigned short)(gd[q] & 0xffff)) * r[2 * q];
    float hi = bf2f((unsigned short)(gd[q] >> 16)) * r[2 * q + 1];
    od[q] = (unsigned int)f2bf(lo) | ((unsigned int)f2bf(hi) << 16);
  }
  *(uint4*)g = out;
}

// ---------- pass B (R13-exact): LDS-staged phi/g, swapped-S, in-register P; grid (128, 8) ----------
// x = ntile*4 + mq ; writes obufP[mq][b][pos][ic]  (pos = (c&1)*2048+n, ic = c>>1)
__global__ __launch_bounds__(256) void k_pv(const unsigned short* __restrict__ thetaT,
    const unsigned short* __restrict__ phiT, const unsigned short* __restrict__ gB,
    unsigned short* __restrict__ obufP) {
  int bx = blockIdx.x;
  int b = blockIdx.y;
  int ntile = bx >> 2, mq = bx & 3;
  int n0 = ntile << 6;
  int t = threadIdx.x; int lane = t & 63; int w = t >> 6;
  int l15 = lane & 15, lg = lane >> 4;
  const unsigned short* tT = thetaT + b * (NN * 64);
  const unsigned short* pT = phiT + b * (NN * 64);
  const unsigned short* gb = gB + b * (64 * NN);
  __shared__ unsigned short phiS[64][72];   // [m-row][k], +8 pad (144B stride, aligned)
  __shared__ unsigned short gS[64][72];     // [c-row][m-col], +8 pad
  __shared__ unsigned int P_u[4][16][33];   // per-wave P, u32-packed
  int nrow = n0 + 16 * w + l15;
  bf8_t at0 = *(const bf8_t*)(tT + nrow * 64 + lg * 8);
  bf8_t at1 = *(const bf8_t*)(tT + nrow * 64 + 32 + lg * 8);
  int srow = t >> 2, spart = t & 3;
  f4_t oacc[4];
#pragma unroll
  for (int ct = 0; ct < 4; ++ct) oacc[ct] = (f4_t){0.f, 0.f, 0.f, 0.f};
  for (int mi = 0; mi < 8; ++mi) {
    int m0 = (mq * 8 + mi) << 6;
    __syncthreads();  // prior iter's LDS reads done
    {
      const uint4* gp = reinterpret_cast<const uint4*>(pT + (m0 + srow) * 64 + spart * 16);
      uint4* lp = reinterpret_cast<uint4*>(&phiS[srow][spart * 16]);
      lp[0] = gp[0];
      lp[1] = gp[1];
      const uint4* gg = reinterpret_cast<const uint4*>(gb + srow * NN + m0 + spart * 16);
      uint4* lg_ = reinterpret_cast<uint4*>(&gS[srow][spart * 16]);
      lg_[0] = gg[0];
      lg_[1] = gg[1];
    }
    __syncthreads();  // tiles ready
#pragma unroll
    for (int mt = 0; mt < 4; ++mt) {
      bf8_t b0 = *(const bf8_t*)&phiS[16 * mt + l15][lg * 8];
      bf8_t b1 = *(const bf8_t*)&phiS[16 * mt + l15][32 + lg * 8];
      f4_t d = {0.f, 0.f, 0.f, 0.f};
      d = MFMA16(b0, at0, d, 0, 0, 0);
      d = MFMA16(b1, at1, d, 0, 0, 0);
      float e0 = __builtin_amdgcn_exp2f(d[0]);
      float e1 = __builtin_amdgcn_exp2f(d[1]);
      float e2 = __builtin_amdgcn_exp2f(d[2]);
      float e3 = __builtin_amdgcn_exp2f(d[3]);
      unsigned int p01, p23;
      asm("v_cvt_pk_bf16_f32 %0, %1, %2" : "=v"(p01) : "v"(e0), "v"(e1));
      asm("v_cvt_pk_bf16_f32 %0, %1, %2" : "=v"(p23) : "v"(e2), "v"(e3));
      P_u[w][l15][8 * mt + 2 * lg] = p01;
      P_u[w][l15][8 * mt + 2 * lg + 1] = p23;
    }
    bf8_t ap0 = *(const bf8_t*)&P_u[w][l15][4 * lg];
    bf8_t ap1 = *(const bf8_t*)&P_u[w][l15][16 + 4 * lg];
#pragma unroll
    for (int ct = 0; ct < 4; ++ct) {
      bf8_t g0 = *(const bf8_t*)&gS[16 * ct + l15][lg * 8];
      bf8_t g1 = *(const bf8_t*)&gS[16 * ct + l15][32 + lg * 8];
      oacc[ct] = MFMA16(ap0, g0, oacc[ct], 0, 0, 0);
      oacc[ct] = MFMA16(ap1, g1, oacc[ct], 0, 0, 0);
    }
  }
  unsigned short* ob = obufP + (mq * 8 + b) * 131072;
#pragma unroll
  for (int ct = 0; ct < 4; ++ct) {
    int c = 16 * ct + l15;
    int nb = n0 + 16 * w + lg * 4;
    int ic = c >> 1;
    int posb = (c & 1) * 2048 + nb;
#pragma unroll
    for (int q = 0; q < 4; ++q)
      ob[(posb + q) * 32 + ic] = f2bf(oacc[ct][q]);
  }
}

// ---------- mask conv via MFMA (mq folded into acc) + residual + pool; grid 512 ----------
// block: b = bx>>6, 64 positions; wave w owns 16 pos; all 64 oc via 4 ct tiles.
// wMl padded to 40 shorts/row (80B) so every LDS b128 access is 16B-aligned.
__global__ __launch_bounds__(256) void k_mask(const unsigned short* __restrict__ obufP,
    const unsigned short* __restrict__ wMbf, const float* __restrict__ scA,
    const float* __restrict__ shA, float* __restrict__ zio,
    float* __restrict__ poolpart) {
  __shared__ unsigned short wMl[64][40];  // [oc][ic] bf16, 80B stride
  __shared__ float red[4][4][16];
  int t = threadIdx.x, lane = t & 63, w = t >> 6;
  int l15 = lane & 15, lg = lane >> 4;
  int bx = blockIdx.x;
  int b = bx >> 6;
  int p0 = (bx & 63) * 64 + w * 16;
  {
    int row = t >> 2, part = t & 3;  // byte addr = row*80 + part*16 : aligned
    *(uint4*)&wMl[row][part * 8] = *(const uint4*)(wMbf + row * 32 + part * 8);
  }
  __syncthreads();
  bf8_t bw[4];
#pragma unroll
  for (int ct = 0; ct < 4; ++ct)
    bw[ct] = *(const bf8_t*)&wMl[16 * ct + l15][lg * 8];
  f4_t acc[4];
#pragma unroll
  for (int ct = 0; ct < 4; ++ct) acc[ct] = (f4_t){0.f, 0.f, 0.f, 0.f};
#pragma unroll
  for (int mq = 0; mq < 4; ++mq) {
    bf8_t a = *(const bf8_t*)(obufP + ((mq * 8 + b) << 17) + (p0 + l15) * 32 + lg * 8);
#pragma unroll
    for (int ct = 0; ct < 4; ++ct)
      acc[ct] = MFMA16(a, bw[ct], acc[ct], 0, 0, 0);
  }
  float* zb = zio + b * (CH * HW);
#pragma unroll
  for (int ct = 0; ct < 4; ++ct) {
    int oc = 16 * ct + l15;
    int pg = p0 + 4 * lg;
    float4 zv = *(const float4*)(zb + oc * HW + pg);
    float sc = scA[oc], sh = shA[oc];
    float4 r;
    r.x = acc[ct][0] + sc * zv.x + sh;
    r.y = acc[ct][1] + sc * zv.y + sh;
    r.z = acc[ct][2] + sc * zv.z + sh;
    r.w = acc[ct][3] + sc * zv.w + sh;
    *(float4*)(zb + oc * HW + pg) = r;
    float s = r.x + r.y + r.z + r.w;
    s += __shfl_xor(s, 16);
    s += __shfl_xor(s, 32);
    if (lg == 0) red[w][ct][l15] = s;
  }
  __syncthreads();
  if (t < 64) {
    int ct = t >> 4, cl = t & 15;
    poolpart[bx * 64 + ct * 16 + cl] =
        red[0][ct][cl] + red[1][ct][cl] + red[2][ct][cl] + red[3][ct][cl];
  }
}

// ---------- head ----------
__global__ __launch_bounds__(256) void k_head(const float* __restrict__ poolpart,
    const float* __restrict__ fcw, const float* __restrict__ fcb,
    const float* __restrict__ bg, const float* __restrict__ bb,
    const float* __restrict__ lx, const float* __restrict__ ly,
    float* __restrict__ outLogit) {
  __shared__ float poolS[8][64];
  __shared__ float fv[8][2];
  __shared__ float gate[8][2];
  int t = threadIdx.x;
  for (int idx = t; idx < 512; idx += 256) {
    int b = idx >> 6, oc = idx & 63;
    float s = 0.f;
    for (int ch = 0; ch < 64; ++ch)
      s += poolpart[((b << 6) + ch) * 64 + oc];
    poolS[b][oc] = s * (1.f / 4096.f);
  }
  __syncthreads();
  if (t < 16) {
    int b = t >> 1, k = t & 1;
    float s = fcb[k];
    for (int c = 0; c < 64; ++c) s += poolS[b][c] * fcw[k * 64 + c];
    fv[b][k] = s;
  }
  __syncthreads();
  if (t < 2) {
    float m = 0.f;
    for (int b = 0; b < 8; ++b) m += fv[b][t];
    m *= 0.125f;
    float v = 0.f;
    for (int b = 0; b < 8; ++b) { float d = fv[b][t] - m; v += d * d; }
    v *= 0.125f;
    float is = rsqrtf(v + 1e-5f);
    for (int b = 0; b < 8; ++b) gate[b][t] = bg[t] * (fv[b][t] - m) * is + bb[t];
  }
  __syncthreads();
  if (t < 8) {
    float a = fmaxf(gate[t][0], 0.f), b2 = fmaxf(gate[t][1], 0.f);
    float mx = fmaxf(a, b2);
    float e0 = __expf(a - mx), e1 = __expf(b2 - mx);
    float inv = 1.f / (e0 + e1);
    gate[t][0] = e0 * inv;
    gate[t][1] = e1 * inv;
  }
  __syncthreads();
  for (int i = t; i < 800; i += 256) {
    int b = i / 100;
    outLogit[i] = gate[b][0] * lx[i] + gate[b][1] * ly[i];
  }
}

extern "C" void kernel_launch(void* const* d_in, const int* in_sizes, int n_in,
                              void* d_out, int out_size, void* d_ws, size_t ws_size,
                              hipStream_t stream) {
  (void)in_sizes; (void)n_in; (void)out_size; (void)ws_size;
  const float* x = (const float*)d_in[0];
  const float* y = (const float*)d_in[1];
  const float* logitx = (const float*)d_in[2];
  const float* logity = (const float*)d_in[3];
  const float* conv1_w = (const float*)d_in[4];
  const float* conv1_b = (const float*)d_in[5];
  const float* bn1_g = (const float*)d_in[6];
  const float* bn1_b = (const float*)d_in[7];
  const float* phi_w = (const float*)d_in[8];
  const float* theta_w = (const float*)d_in[9];
  const float* g_w = (const float*)d_in[10];
  const float* mask_w = (const float*)d_in[11];
  const float* fc_w = (const float*)d_in[12];
  const float* fc_b = (const float*)d_in[13];
  const float* bnv_g = (const float*)d_in[14];
  const float* bnv_b = (const float*)d_in[15];

  unsigned short* U = (unsigned short*)d_ws;
  float* F = (float*)d_ws;
  unsigned short* thetaT = U;                   // 2 MB
  unsigned short* phiT   = U + 1048576;         // 2 MB
  unsigned short* gB     = U + 2097152;         // 2 MB
  unsigned short* obufP  = U + 3145728;         // 8 MB (4 mq x 8 b x 4096 pos x 32 ic)
  float* csum      = F + 3670016;               // 65536 floats (b*8192 stride)
  float* poolpart  = F + 3670016;               // ALIAS of csum: csum consumed by gscale
                                                // (kernel 5) before k_mask (kernel 7) writes
  float2* partials = (float2*)(F + 3735552);    // 128*4*16 float2 (16384 floats)
  float* effw      = F + 3751936;               // 6144
  float* effb      = F + 3758080;               // 96 (pad 128)
  unsigned short* wMbf = (unsigned short*)(F + 3758208);  // 2048 shorts (1024 floats)
  float* scA       = F + 3759232;               // 64
  float* shA       = F + 3759296;               // 64 -> end F+3759360 (~14.3 MB)

  float* zout = (float*)d_out;        // z then feasc in-place
  float* lout = zout + 2097152;       // logit

  k_conv1<<<dim3(128, 4), 256, 0, stream>>>(x, y, conv1_w, conv1_b, zout, partials);
  k_prep1<<<1, 256, 0, stream>>>(partials, phi_w, theta_w, g_w, mask_w,
                                 bn1_g, bn1_b, effw, effb, wMbf, scA, shA);
  k_proj<<<dim3(128, 6), 256, 0, stream>>>(zout, effw, effb, phiT, thetaT, gB);
  k_colsum<<<dim3(128, 8), 256, 0, stream>>>(thetaT, phiT, csum);
  k_gscale<<<512, 256, 0, stream>>>(csum, gB);
  k_pv<<<dim3(128, 8), 256, 0, stream>>>(thetaT, phiT, gB, obufP);
  k_mask<<<512, 256, 0, stream>>>(obufP, wMbf, scA, shA, zout, poolpart);
  k_head<<<1, 256, 0, stream>>>(poolpart, fc_w, fc_b, bnv_g, bnv_b, logitx, logity, lout);
}